// Round 2
// 296.903 us; speedup vs baseline: 1.0593x; 1.0593x over previous
//
#include <hip/hip_runtime.h>
#include <stdint.h>

#define DIM  1024
#define NSRC 4096
#define NTGT 4096

typedef __bf16 bf16_t;
typedef bf16_t bf16x8 __attribute__((ext_vector_type(8)));
typedef float  fx4    __attribute__((ext_vector_type(4)));

static __device__ __forceinline__ unsigned short f2bf(float f) {
  union { float f; uint32_t u; } v; v.f = f;
  return (unsigned short)((v.u + 0x7FFFu + ((v.u >> 16) & 1u)) >> 16);
}
static __device__ __forceinline__ float bf2f(unsigned short h) {
  union { uint32_t u; float f; } v; v.u = ((uint32_t)h) << 16;
  return v.f;
}

// async global->LDS, 16B per lane; lds dest is wave-uniform base + lane*16
static __device__ __forceinline__ void gl_lds16(const unsigned short* g, unsigned short* l) {
  __builtin_amdgcn_global_load_lds(
      (__attribute__((address_space(1))) const void*)g,
      (__attribute__((address_space(3))) void*)l, 16, 0, 0);
}

// Permutation within each 64-element block: stored s holds true (s>>2)+16*(s&3).
// Inverse (true c comes from stored): p(c) = (c&15)*4 + (c>>4).

// ---------------- fused fp32->bf16 conversion of all four inputs ----------------
__global__ void k_convert_all(const float* __restrict__ s, const float* __restrict__ t,
                              const float* __restrict__ w0, const float* __restrict__ w1,
                              unsigned short* __restrict__ sb, unsigned short* __restrict__ tb,
                              unsigned short* __restrict__ wb0, unsigned short* __restrict__ wb1) {
  int b = blockIdx.x;
  const float* in; unsigned short* out; int idx;
  if (b < 4096)      { in = s;  out = sb;  idx = b * 256 + threadIdx.x; }
  else if (b < 8192) { in = t;  out = tb;  idx = (b - 4096) * 256 + threadIdx.x; }
  else if (b < 9216) { in = w0; out = wb0; idx = (b - 8192) * 256 + threadIdx.x; }
  else               { in = w1; out = wb1; idx = (b - 9216) * 256 + threadIdx.x; }
  float4 v = ((const float4*)in)[idx];
  ushort4 o;
  o.x = f2bf(v.x); o.y = f2bf(v.y); o.z = f2bf(v.z); o.w = f2bf(v.w);
  ((ushort4*)out)[idx] = o;
}

// transpose fp32 target [R=NTGT][C=DIM] -> bf16 tgtT_b[n][s] = target[true(s)][n]
__global__ void k_transpose_bf16(const float* __restrict__ in, unsigned short* __restrict__ out,
                                 int R, int C) {
  __shared__ unsigned short tile[32][33];
  int c0 = blockIdx.x * 32, r0 = blockIdx.y * 32;
  int tx = threadIdx.x, ty = threadIdx.y; // 32 x 8
  for (int i = ty; i < 32; i += 8) {
    int row = r0 + i;
    int p = row & 63;
    int tr = (row & ~63) | ((p >> 2) | ((p & 3) << 4)); // true(row)
    tile[i][tx] = f2bf(in[(size_t)tr * C + c0 + tx]);
  }
  __syncthreads();
  for (int i = ty; i < 32; i += 8)
    out[(size_t)(c0 + i) * R + r0 + tx] = tile[tx][i];
}

// ---------------- finalize (split: no parts-read / K-write overlap race) ----------------
// aligned = sum(P[0..1]) / rs   (z=2 split-K partials)
__global__ void k_finalize_aligned(const float* __restrict__ P, float* __restrict__ aligned,
                                   const float* __restrict__ rs) {
  const int b = blockIdx.x;
  const int lane = threadIdx.x & 63, w = threadIdx.x >> 6;
  const int src = ((lane & 15) << 2) | (lane >> 4);
  const size_t stride = (size_t)NSRC * DIM;
#pragma unroll
  for (int it = 0; it < 4; ++it) {
    int idx = b * 16 + w * 4 + it;   // 64-block index; 16 per row of DIM
    size_t base = (size_t)idx * 64;
    float r = 1.0f / rs[idx >> 4];
    float v = (P[base + lane] + P[base + stride + lane]) * r;
    aligned[base + lane] = __shfl(v, src, 64);
  }
}

// K = bf2f(Eb)/rs (un-permuted)
__global__ void k_finalize_K(const unsigned short* __restrict__ Eb, float* __restrict__ Kf,
                             const float* __restrict__ rs) {
  const int b = blockIdx.x;
  const int lane = threadIdx.x & 63, w = threadIdx.x >> 6;
  const int src = ((lane & 15) << 2) | (lane >> 4);
#pragma unroll
  for (int it = 0; it < 8; ++it) {
    int idx = b * 32 + w * 8 + it;  // 64-block index; 64 per row of NTGT
    size_t base = (size_t)idx * 64;
    float r = 1.0f / rs[idx >> 6];
    float v = bf2f(Eb[base + lane]) * r;
    Kf[base + lane] = __shfl(v, src, 64);
  }
}

// ---------------- m97-style NT bf16 GEMM, 128x128 tile, BK=32, 256 threads ----------------
// EPI 0: dual proj (z selects set), +bias, bf16 out; row-sumsq atomics
// EPI 3: split-K (z = k-chunk), fp32 partial float4 stores
template <int EPI>
__global__ void __launch_bounds__(256)
k_gemm(const unsigned short* __restrict__ A0, const unsigned short* __restrict__ B0,
       const unsigned short* __restrict__ A1, const unsigned short* __restrict__ B1,
       int N, int K,
       const float* __restrict__ bias0, const float* __restrict__ bias1,
       unsigned short* __restrict__ Cb0, unsigned short* __restrict__ Cb1,
       float* __restrict__ Cf,
       const float* __restrict__ sqs, const float* __restrict__ sqt,
       const float* __restrict__ tempPtr,
       float* __restrict__ red0, float* __restrict__ red1,
       int KS) {
  __shared__ unsigned short ldsA[128 * 32];
  __shared__ unsigned short ldsB[128 * 32];
  __shared__ float rsum[128];

  const unsigned short* A = A0;
  const unsigned short* B = B0;
  const float* bias = bias0;
  unsigned short* Cb = Cb0;
  float* red = red0;
  int k0 = 0, k1 = K;
  if constexpr (EPI == 0) {
    if (blockIdx.z) { A = A1; B = B1; bias = bias1; Cb = Cb1; red = red1; }
  }
  if constexpr (EPI == 3) { k0 = blockIdx.z * KS; k1 = k0 + KS; }

  const int m0 = blockIdx.y * 128;
  const int n0 = blockIdx.x * 128;
  const int tid  = threadIdx.x;
  const int lane = tid & 63;
  const int wv   = tid >> 6;
  const int wm   = wv >> 1, wn = wv & 1;

  const int c0    = wv * 2;
  const int srow  = lane >> 2;
  const int skoff = (lane & 3) * 8;
  const unsigned short* ag[2]; const unsigned short* bg[2];
  unsigned short* la[2]; unsigned short* lb[2];
#pragma unroll
  for (int j = 0; j < 2; ++j) {
    int c = c0 + j;
    ag[j] = A + (size_t)(m0 + c * 16 + srow) * K + skoff;
    bg[j] = B + (size_t)(n0 + c * 16 + srow) * K + skoff;
    la[j] = ldsA + c * 512;
    lb[j] = ldsB + c * 512;
  }

  const fx4 fzero = {0.f, 0.f, 0.f, 0.f};
  fx4 acc[4][4];
#pragma unroll
  for (int i = 0; i < 4; ++i)
#pragma unroll
    for (int j = 0; j < 4; ++j) acc[i][j] = fzero;

  const int frow = lane & 15;
  const int kq   = lane >> 4;
  const int aoff = (wm * 64 + frow) * 32 + kq * 8;
  const int boff = (wn * 64 + frow) * 32 + kq * 8;

  for (int ko = k0; ko < k1; ko += 32) {
    gl_lds16(ag[0] + ko, la[0]);
    gl_lds16(ag[1] + ko, la[1]);
    gl_lds16(bg[0] + ko, lb[0]);
    gl_lds16(bg[1] + ko, lb[1]);
    __syncthreads();
    bf16x8 af[4], bfr[4];
#pragma unroll
    for (int t = 0; t < 4; ++t) af[t]  = *(const bf16x8*)(ldsA + aoff + t * 512);
#pragma unroll
    for (int t = 0; t < 4; ++t) bfr[t] = *(const bf16x8*)(ldsB + boff + t * 512);
#pragma unroll
    for (int i = 0; i < 4; ++i)
#pragma unroll
      for (int j = 0; j < 4; ++j)
        acc[i][j] = __builtin_amdgcn_mfma_f32_16x16x32_bf16(af[i], bfr[j], acc[i][j], 0, 0, 0);
    __syncthreads();
  }

  const int gcol0 = n0 + wn * 64 + frow;      // true col (for bias/sqt), + j*16
  const int scol  = n0 + wn * 64 + frow * 4;  // stored col base

  if constexpr (EPI == 0) {
    if (tid < 128) rsum[tid] = 0.f;
    __syncthreads();
#pragma unroll
    for (int i = 0; i < 4; ++i)
#pragma unroll
      for (int r = 0; r < 4; ++r) {
        const int lrow = wm * 64 + kq * 4 + i * 16 + r;
        const int gm   = m0 + lrow;
        float racc = 0.f;
        ushort4 o;
        unsigned short* op = (unsigned short*)&o;
#pragma unroll
        for (int j = 0; j < 4; ++j) {
          float e = acc[i][j][r] + bias[gcol0 + j * 16];
          unsigned short eb = f2bf(e);
          op[j] = eb;
          float ev = bf2f(eb);
          racc += ev * ev; // sumsq of ROUNDED value
        }
        *(ushort4*)(Cb + (size_t)gm * N + scol) = o;
        racc += __shfl_xor(racc, 1, 64);
        racc += __shfl_xor(racc, 2, 64);
        racc += __shfl_xor(racc, 4, 64);
        racc += __shfl_xor(racc, 8, 64);
        if (frow == 0) atomicAdd(&rsum[lrow], racc);
      }
    __syncthreads();
    if (tid < 128) atomicAdd(&red[m0 + tid], rsum[tid]);
  } else { // EPI == 3: fp32 partials, permuted float4 stores
    float* Pz = Cf + (size_t)blockIdx.z * NSRC * DIM;
#pragma unroll
    for (int i = 0; i < 4; ++i)
#pragma unroll
      for (int r = 0; r < 4; ++r) {
        const int gm = m0 + wm * 64 + kq * 4 + i * 16 + r;
        float4 v = make_float4(acc[i][0][r], acc[i][1][r], acc[i][2][r], acc[i][3][r]);
        *(float4*)(Pz + (size_t)gm * N + scol) = v;
      }
  }
}

// ---------------- 256x256 8-phase score GEMM (T2+T3+T4+T5), M=N=4096, K=1024 ----------------
// A = sp_b [4096][1024], B = tp_b [4096][1024], both NT (row-major, K contiguous),
// both with the SAME K-permutation (dot products invariant).
// LDS layout per operand: [buf(2)][ksb(2)][stripe(16)][16 rows][32 k] bf16, st_16x32
// XOR-swizzle: subtile-local byte ^= 32 when row-in-stripe >= 8; applied on the
// GLOBAL source address at stage time (gl_lds dest is linear) and on ds_read addr.
// LDS total = exactly 128 KiB (the HW-verified 8-phase template footprint).
__global__ void __launch_bounds__(512, 2)
k_score256(const unsigned short* __restrict__ A, const unsigned short* __restrict__ B,
           unsigned short* __restrict__ Eb,
           const float* __restrict__ sqs, const float* __restrict__ sqt,
           const float* __restrict__ tempPtr, float* __restrict__ rsums) {
  __shared__ unsigned short ldsA[32768]; // 64 KB
  __shared__ unsigned short ldsB[32768]; // 64 KB

  const int tid = threadIdx.x;
  const int lane = tid & 63, w = tid >> 6;   // 8 waves
  const int wm = w >> 2, wn = w & 3;         // 2 x 4
  const int fr = lane & 15, kq = lane >> 4;
  const int m0 = blockIdx.y * 256, n0 = blockIdx.x * 256;

  // stage: wave w instr n covers stripe (n*8+w); lane -> (row-in-stripe, swizzled k-col)
  const int rin = lane >> 2;
  const int cs  = ((lane & 3) * 8) ^ ((lane >> 5) ? 16 : 0); // inverse-swizzled source col
  const size_t aoff0 = (size_t)(m0 + w * 16 + rin) * DIM + cs;
  const size_t aoff1 = (size_t)(m0 + (8 + w) * 16 + rin) * DIM + cs;
  const size_t boff0 = (size_t)(n0 + w * 16 + rin) * DIM + cs;
  const size_t boff1 = (size_t)(n0 + (8 + w) * 16 + rin) * DIM + cs;

  // ds_read per-lane offset (shorts), swizzled
  const int roA = fr * 32 + ((kq * 8) ^ ((fr & 8) ? 16 : 0));

#define STAGE_A(buf, ksb, kk) do { \
    gl_lds16(A + aoff0 + (kk) + (ksb) * 32, ldsA + (buf) * 16384 + (ksb) * 8192 + w * 512); \
    gl_lds16(A + aoff1 + (kk) + (ksb) * 32, ldsA + (buf) * 16384 + (ksb) * 8192 + (8 + w) * 512); \
  } while (0)
#define STAGE_B(buf, ksb, kk) do { \
    gl_lds16(B + boff0 + (kk) + (ksb) * 32, ldsB + (buf) * 16384 + (ksb) * 8192 + w * 512); \
    gl_lds16(B + boff1 + (kk) + (ksb) * 32, ldsB + (buf) * 16384 + (ksb) * 8192 + (8 + w) * 512); \
  } while (0)

  const fx4 fz = {0.f, 0.f, 0.f, 0.f};
  fx4 acc[8][4];
#pragma unroll
  for (int i = 0; i < 8; ++i)
#pragma unroll
    for (int j = 0; j < 4; ++j) acc[i][j] = fz;

  bf16x8 a[8], b0v, b1v;

#define LDA8(buf, ks) do { _Pragma("unroll") \
    for (int i = 0; i < 8; ++i) \
      a[i] = *(const bf16x8*)(ldsA + (buf) * 16384 + (ks) * 8192 + (wm * 8 + i) * 512 + roA); \
  } while (0)
#define LDB2(buf, ks, jh) do { \
    b0v = *(const bf16x8*)(ldsB + (buf) * 16384 + (ks) * 8192 + (wn * 4 + (jh) * 2) * 512 + roA); \
    b1v = *(const bf16x8*)(ldsB + (buf) * 16384 + (ks) * 8192 + (wn * 4 + (jh) * 2 + 1) * 512 + roA); \
  } while (0)
#define MFMA16(jh) do { _Pragma("unroll") \
    for (int i = 0; i < 8; ++i) { \
      acc[i][(jh) * 2]     = __builtin_amdgcn_mfma_f32_16x16x32_bf16(a[i], b0v, acc[i][(jh) * 2], 0, 0, 0); \
      acc[i][(jh) * 2 + 1] = __builtin_amdgcn_mfma_f32_16x16x32_bf16(a[i], b1v, acc[i][(jh) * 2 + 1], 0, 0, 0); \
    } } while (0)
#define BAR()   __builtin_amdgcn_s_barrier()
#define SB0()   __builtin_amdgcn_sched_barrier(0)
#define LGKM0() asm volatile("s_waitcnt lgkmcnt(0)" ::: "memory")
#define VM6()   asm volatile("s_waitcnt vmcnt(6)" ::: "memory")

  // prologue: tile0 -> buf0 (k=0) full; tile1 -> buf1 (k=64) minus B-ks1
  STAGE_A(0, 0, 0);  STAGE_B(0, 0, 0);  STAGE_A(0, 1, 0);  STAGE_B(0, 1, 0);
  STAGE_A(1, 0, 64); STAGE_B(1, 0, 64); STAGE_A(1, 1, 64);
  VM6(); // buf0 complete; 3 half-tiles in flight (steady P8 state)
  SB0(); BAR();

#pragma unroll 1
  for (int it = 0; it < 8; ++it) {
    const int kk1 = it * 128 + 64;                // tile 2it+1 (its B-ks1, staged at P1)
    const int kk2 = (it * 128 + 128) & (DIM - 1); // tile 2it+2 -> buf0 (wraps harmlessly)
    const int kk3 = (it * 128 + 192) & (DIM - 1); // tile 2it+3 -> buf1
    // P1
    LDA8(0, 0); LDB2(0, 0, 0); STAGE_B(1, 1, kk1);
    SB0(); BAR(); LGKM0();
    __builtin_amdgcn_s_setprio(1); MFMA16(0); __builtin_amdgcn_s_setprio(0);
    SB0(); BAR();
    // P2
    LDB2(0, 0, 1); STAGE_A(0, 0, kk2);
    SB0(); BAR(); LGKM0();
    __builtin_amdgcn_s_setprio(1); MFMA16(1); __builtin_amdgcn_s_setprio(0);
    SB0(); BAR();
    // P3
    LDA8(0, 1); LDB2(0, 1, 0); STAGE_B(0, 0, kk2);
    SB0(); BAR(); LGKM0();
    __builtin_amdgcn_s_setprio(1); MFMA16(0); __builtin_amdgcn_s_setprio(0);
    SB0(); BAR();
    // P4
    LDB2(0, 1, 1); STAGE_A(0, 1, kk2);
    SB0(); BAR(); LGKM0();
    __builtin_amdgcn_s_setprio(1); MFMA16(1); __builtin_amdgcn_s_setprio(0);
    VM6(); // gates buf1 reads (P5-P8): everything issued <= P1 has landed
    SB0(); BAR();
    // P5
    LDA8(1, 0); LDB2(1, 0, 0); STAGE_B(0, 1, kk2);
    SB0(); BAR(); LGKM0();
    __builtin_amdgcn_s_setprio(1); MFMA16(0); __builtin_amdgcn_s_setprio(0);
    SB0(); BAR();
    // P6
    LDB2(1, 0, 1); STAGE_A(1, 0, kk3);
    SB0(); BAR(); LGKM0();
    __builtin_amdgcn_s_setprio(1); MFMA16(1); __builtin_amdgcn_s_setprio(0);
    SB0(); BAR();
    // P7
    LDA8(1, 1); LDB2(1, 1, 0); STAGE_B(1, 0, kk3);
    SB0(); BAR(); LGKM0();
    __builtin_amdgcn_s_setprio(1); MFMA16(0); __builtin_amdgcn_s_setprio(0);
    SB0(); BAR();
    // P8
    LDB2(1, 1, 1); STAGE_A(1, 1, kk3);
    SB0(); BAR(); LGKM0();
    __builtin_amdgcn_s_setprio(1); MFMA16(1); __builtin_amdgcn_s_setprio(0);
    VM6(); // gates buf0 reads (next P1-P4): everything issued <= P5 has landed
    SB0(); BAR();
  }
  asm volatile("s_waitcnt vmcnt(0)" ::: "memory");
  __syncthreads();

  // epilogue: E = exp(-sqrt(max(sqs+sqt-2c,0))/T), permuted bf16 store, row sums
  // row-sum: 4-lane shuffle reduce then direct global atomics (64 adds/row grid-wide)
  const float invT = 1.0f / tempPtr[0];
  const int gcol0 = n0 + wn * 64 + fr;      // true col, + j*16
  const int scol  = n0 + wn * 64 + fr * 4;  // permuted stored col base
#pragma unroll
  for (int i = 0; i < 8; ++i)
#pragma unroll
    for (int r = 0; r < 4; ++r) {
      const int lrow = wm * 128 + i * 16 + kq * 4 + r;
      const int gm = m0 + lrow;
      const float si = sqs[gm];
      float racc = 0.f;
      ushort4 o; unsigned short* op = (unsigned short*)&o;
#pragma unroll
      for (int j = 0; j < 4; ++j) {
        float d2 = si + sqt[gcol0 + j * 16] - 2.0f * acc[i][j][r];
        float c = sqrtf(fmaxf(d2, 0.0f));
        unsigned short eb = f2bf(__expf(-c * invT));
        op[j] = eb;
        racc += bf2f(eb);
      }
      *(ushort4*)(Eb + (size_t)gm * NTGT + scol) = o;
      racc += __shfl_xor(racc, 1, 64);
      racc += __shfl_xor(racc, 2, 64);
      racc += __shfl_xor(racc, 4, 64);
      racc += __shfl_xor(racc, 8, 64);
      if (fr == 0) atomicAdd(&rsums[gm], racc);
    }
#undef STAGE_A
#undef STAGE_B
#undef LDA8
#undef LDB2
#undef MFMA16
#undef BAR
#undef SB0
#undef LGKM0
#undef VM6
}

// ---------------- launch ----------------
extern "C" void kernel_launch(void* const* d_in, const int* in_sizes, int n_in,
                              void* d_out, int out_size, void* d_ws, size_t ws_size,
                              hipStream_t stream) {
  const float* source = (const float*)d_in[0];
  const float* target = (const float*)d_in[1];
  const float* W_src  = (const float*)d_in[2];
  const float* b_src  = (const float*)d_in[3];
  const float* W_tgt  = (const float*)d_in[4];
  const float* b_tgt  = (const float*)d_in[5];
  const float* temp   = (const float*)d_in[6];

  float* out     = (float*)d_out;
  float* aligned = out;                         // [NSRC][DIM]
  float* Kout    = out + (size_t)NSRC * DIM;    // final K; staging for split-K partials
  float* parts   = Kout;                        // 2 x [NSRC][DIM] fp32 = 32 MB

  char* ws = (char*)d_ws;
  unsigned short* src_b  = (unsigned short*)(ws + 0);
  unsigned short* tgt_b  = (unsigned short*)(ws + 8388608);
  unsigned short* Wsrc_b = (unsigned short*)(ws + 16777216);
  unsigned short* Wtgt_b = (unsigned short*)(ws + 18874368);
  unsigned short* sp_b   = (unsigned short*)(ws + 20971520);
  unsigned short* tp_b   = (unsigned short*)(ws + 29360128);
  unsigned short* tgtT_b = (unsigned short*)(ws + 37748736);
  unsigned short* E_b    = (unsigned short*)(ws + 46137344); // 32 MB
  float* sq_s  = (float*)(ws + 79691776);                    // 16 KB
  float* sq_t  = (float*)(ws + 79708160);                    // 16 KB
  float* rsums = (float*)(ws + 79724544);                    // 16 KB

  // 0) zero sq_s, sq_t, rsums (contiguous 48 KB)
  hipMemsetAsync(sq_s, 0, 3 * NSRC * sizeof(float), stream);

  // 1) conversions + permuted target transpose
  k_convert_all<<<10240, 256, 0, stream>>>(source, target, W_src, W_tgt,
                                           src_b, tgt_b, Wsrc_b, Wtgt_b);
  k_transpose_bf16<<<dim3(DIM / 32, NTGT / 32), dim3(32, 8), 0, stream>>>(target, tgtT_b, NTGT, DIM);

  // 2) both projections (z selects problem); outputs permuted in DIM; row-sumsq fused
  k_gemm<0><<<dim3(DIM / 128, NSRC / 128, 2), 256, 0, stream>>>(
      src_b, Wsrc_b, tgt_b, Wtgt_b, DIM, DIM, b_src, b_tgt, sp_b, tp_b,
      nullptr, nullptr, nullptr, nullptr, sq_s, sq_t, 0);

  // 3) score: 256x256 8-phase GEMM; E bf16 (permuted in NTGT) -> ws, row sums -> rsums
  k_score256<<<dim3(NTGT / 256, NSRC / 256), 512, 0, stream>>>(
      sp_b, tp_b, E_b, sq_s, sq_t, temp, rsums);

  // 4) E @ target: split-K x2, permuted float4 partial stores into d_out K region
  k_gemm<3><<<dim3(DIM / 128, NSRC / 128, 2), 256, 0, stream>>>(
      E_b, tgtT_b, nullptr, nullptr, DIM, NTGT, nullptr, nullptr, nullptr, nullptr,
      parts, nullptr, nullptr, nullptr, nullptr, nullptr, NTGT / 2);

  // 5) finalize: aligned first (reads parts), then K (overwrites parts region)
  k_finalize_aligned<<<4096, 256, 0, stream>>>(parts, aligned, rsums);
  k_finalize_K<<<8192, 256, 0, stream>>>(E_b, Kout, rsums);
}

// Round 3
// 280.213 us; speedup vs baseline: 1.1224x; 1.0596x over previous
//
#include <hip/hip_runtime.h>
#include <stdint.h>

#define DIM  1024
#define NSRC 4096
#define NTGT 4096

typedef __bf16 bf16_t;
typedef bf16_t bf16x8 __attribute__((ext_vector_type(8)));
typedef float  fx4    __attribute__((ext_vector_type(4)));

static __device__ __forceinline__ unsigned short f2bf(float f) {
  union { float f; uint32_t u; } v; v.f = f;
  return (unsigned short)((v.u + 0x7FFFu + ((v.u >> 16) & 1u)) >> 16);
}
static __device__ __forceinline__ float bf2f(unsigned short h) {
  union { uint32_t u; float f; } v; v.u = ((uint32_t)h) << 16;
  return v.f;
}

// async global->LDS, 16B per lane; lds dest is wave-uniform base + lane*16
static __device__ __forceinline__ void gl_lds16(const unsigned short* g, unsigned short* l) {
  __builtin_amdgcn_global_load_lds(
      (__attribute__((address_space(1))) const void*)g,
      (__attribute__((address_space(3))) void*)l, 16, 0, 0);
}

// Permutation within each 64-element block: stored s holds true (s>>2)+16*(s&3).
// Inverse (true c comes from stored): p(c) = (c&15)*4 + (c>>4).

// ---------------- fused fp32->bf16 conversion of all four inputs ----------------
__global__ void k_convert_all(const float* __restrict__ s, const float* __restrict__ t,
                              const float* __restrict__ w0, const float* __restrict__ w1,
                              unsigned short* __restrict__ sb, unsigned short* __restrict__ tb,
                              unsigned short* __restrict__ wb0, unsigned short* __restrict__ wb1) {
  int b = blockIdx.x;
  const float* in; unsigned short* out; int idx;
  if (b < 4096)      { in = s;  out = sb;  idx = b * 256 + threadIdx.x; }
  else if (b < 8192) { in = t;  out = tb;  idx = (b - 4096) * 256 + threadIdx.x; }
  else if (b < 9216) { in = w0; out = wb0; idx = (b - 8192) * 256 + threadIdx.x; }
  else               { in = w1; out = wb1; idx = (b - 9216) * 256 + threadIdx.x; }
  float4 v = ((const float4*)in)[idx];
  ushort4 o;
  o.x = f2bf(v.x); o.y = f2bf(v.y); o.z = f2bf(v.z); o.w = f2bf(v.w);
  ((ushort4*)out)[idx] = o;
}

// transpose fp32 target [R=NTGT][C=DIM] -> bf16 tgtT_b[n][s] = target[true(s)][n]
__global__ void k_transpose_bf16(const float* __restrict__ in, unsigned short* __restrict__ out,
                                 int R, int C) {
  __shared__ unsigned short tile[32][33];
  int c0 = blockIdx.x * 32, r0 = blockIdx.y * 32;
  int tx = threadIdx.x, ty = threadIdx.y; // 32 x 8
  for (int i = ty; i < 32; i += 8) {
    int row = r0 + i;
    int p = row & 63;
    int tr = (row & ~63) | ((p >> 2) | ((p & 3) << 4)); // true(row)
    tile[i][tx] = f2bf(in[(size_t)tr * C + c0 + tx]);
  }
  __syncthreads();
  for (int i = ty; i < 32; i += 8)
    out[(size_t)(c0 + i) * R + r0 + tx] = tile[tx][i];
}

// ---------------- finalize ----------------
// aligned = sum(P[0..3]) / rs   (z=4 split-K partials)
__global__ void k_finalize_aligned(const float* __restrict__ P, float* __restrict__ aligned,
                                   const float* __restrict__ rs) {
  const int b = blockIdx.x;
  const int lane = threadIdx.x & 63, w = threadIdx.x >> 6;
  const int src = ((lane & 15) << 2) | (lane >> 4);
  const size_t stride = (size_t)NSRC * DIM;
#pragma unroll
  for (int it = 0; it < 4; ++it) {
    int idx = b * 16 + w * 4 + it;   // 64-block index; 16 per row of DIM
    size_t base = (size_t)idx * 64;
    float r = 1.0f / rs[idx >> 4];
    float v = (P[base + lane] + P[base + stride + lane] +
               P[base + 2 * stride + lane] + P[base + 3 * stride + lane]) * r;
    aligned[base + lane] = __shfl(v, src, 64);
  }
}

// K = bf2f(Eb)/rs (un-permuted)
__global__ void k_finalize_K(const unsigned short* __restrict__ Eb, float* __restrict__ Kf,
                             const float* __restrict__ rs) {
  const int b = blockIdx.x;
  const int lane = threadIdx.x & 63, w = threadIdx.x >> 6;
  const int src = ((lane & 15) << 2) | (lane >> 4);
#pragma unroll
  for (int it = 0; it < 8; ++it) {
    int idx = b * 32 + w * 8 + it;  // 64-block index; 64 per row of NTGT
    size_t base = (size_t)idx * 64;
    float r = 1.0f / rs[idx >> 6];
    float v = bf2f(Eb[base + lane]) * r;
    Kf[base + lane] = __shfl(v, src, 64);
  }
}

// ---------------- 256x256 8-phase GEMM template (T2+T3+T4+T5) ----------------
// NT bf16: A [M rows][LDK k], B [N rows][LDK k], both row-major K-contiguous,
// both with the SAME K-permutation (dot products invariant).
// K-chunk is always 1024 (8 iterations of the verified 8-phase loop).
// LDS: [buf(2)][ksb(2)][stripe(16)][16 rows][32 k] bf16, st_16x32 XOR-swizzle
// applied on the GLOBAL source col (gl_lds dest is linear) and on ds_read addr.
// EPI 0: proj: z selects (A,B,bias,out,red); +bias, permuted bf16 out, row-sumsq atomics
// EPI 1: score: E=exp(-sqrt(max(sqs+sqt-2c,0))/T) permuted bf16 out, row-sum atomics
// EPI 3: split-K PV: z = k-chunk; fp32 partial float4 stores (permuted cols)
template <int EPI, int LDK>
__global__ void __launch_bounds__(512, 2)
k_tile256(const unsigned short* __restrict__ A0, const unsigned short* __restrict__ B0,
          const unsigned short* __restrict__ A1, const unsigned short* __restrict__ B1,
          const float* __restrict__ bias0, const float* __restrict__ bias1,
          unsigned short* __restrict__ Cb0, unsigned short* __restrict__ Cb1,
          unsigned short* __restrict__ Eb, float* __restrict__ Cf,
          const float* __restrict__ sqs, const float* __restrict__ sqt,
          const float* __restrict__ tempPtr,
          float* __restrict__ red0, float* __restrict__ red1) {
  __shared__ unsigned short ldsA[32768]; // 64 KB
  __shared__ unsigned short ldsB[32768]; // 64 KB

  const unsigned short* A = A0;
  const unsigned short* B = B0;
  const float* bias = bias0;
  unsigned short* Cb = Cb0;
  float* red = red0;
  if constexpr (EPI == 0) {
    if (blockIdx.z) { A = A1; B = B1; bias = bias1; Cb = Cb1; red = red1; }
  }
  if constexpr (EPI == 3) { A += blockIdx.z * 1024; B += blockIdx.z * 1024; }

  const int tid = threadIdx.x;
  const int lane = tid & 63, w = tid >> 6;   // 8 waves
  const int wm = w >> 2, wn = w & 3;         // 2 x 4
  const int fr = lane & 15, kq = lane >> 4;
  const int m0 = blockIdx.y * 256, n0 = blockIdx.x * 256;

  // stage: wave w instr n covers stripe (n*8+w); lane -> (row-in-stripe, swizzled k-col)
  const int rin = lane >> 2;
  const int cs  = ((lane & 3) * 8) ^ ((lane >> 5) ? 16 : 0); // inverse-swizzled source col
  const size_t aoff0 = (size_t)(m0 + w * 16 + rin) * LDK + cs;
  const size_t aoff1 = (size_t)(m0 + (8 + w) * 16 + rin) * LDK + cs;
  const size_t boff0 = (size_t)(n0 + w * 16 + rin) * LDK + cs;
  const size_t boff1 = (size_t)(n0 + (8 + w) * 16 + rin) * LDK + cs;

  // ds_read per-lane offset (shorts), swizzled
  const int roA = fr * 32 + ((kq * 8) ^ ((fr & 8) ? 16 : 0));

#define STAGE_A(buf, ksb, kk) do { \
    gl_lds16(A + aoff0 + (kk) + (ksb) * 32, ldsA + (buf) * 16384 + (ksb) * 8192 + w * 512); \
    gl_lds16(A + aoff1 + (kk) + (ksb) * 32, ldsA + (buf) * 16384 + (ksb) * 8192 + (8 + w) * 512); \
  } while (0)
#define STAGE_B(buf, ksb, kk) do { \
    gl_lds16(B + boff0 + (kk) + (ksb) * 32, ldsB + (buf) * 16384 + (ksb) * 8192 + w * 512); \
    gl_lds16(B + boff1 + (kk) + (ksb) * 32, ldsB + (buf) * 16384 + (ksb) * 8192 + (8 + w) * 512); \
  } while (0)

  const fx4 fz = {0.f, 0.f, 0.f, 0.f};
  fx4 acc[8][4];
#pragma unroll
  for (int i = 0; i < 8; ++i)
#pragma unroll
    for (int j = 0; j < 4; ++j) acc[i][j] = fz;

  bf16x8 a[8], b0v, b1v;

#define LDA8(buf, ks) do { _Pragma("unroll") \
    for (int i = 0; i < 8; ++i) \
      a[i] = *(const bf16x8*)(ldsA + (buf) * 16384 + (ks) * 8192 + (wm * 8 + i) * 512 + roA); \
  } while (0)
#define LDB2(buf, ks, jh) do { \
    b0v = *(const bf16x8*)(ldsB + (buf) * 16384 + (ks) * 8192 + (wn * 4 + (jh) * 2) * 512 + roA); \
    b1v = *(const bf16x8*)(ldsB + (buf) * 16384 + (ks) * 8192 + (wn * 4 + (jh) * 2 + 1) * 512 + roA); \
  } while (0)
#define MFMA16(jh) do { _Pragma("unroll") \
    for (int i = 0; i < 8; ++i) { \
      acc[i][(jh) * 2]     = __builtin_amdgcn_mfma_f32_16x16x32_bf16(a[i], b0v, acc[i][(jh) * 2], 0, 0, 0); \
      acc[i][(jh) * 2 + 1] = __builtin_amdgcn_mfma_f32_16x16x32_bf16(a[i], b1v, acc[i][(jh) * 2 + 1], 0, 0, 0); \
    } } while (0)
#define BAR()   __builtin_amdgcn_s_barrier()
#define SB0()   __builtin_amdgcn_sched_barrier(0)
#define LGKM0() asm volatile("s_waitcnt lgkmcnt(0)" ::: "memory")
#define VM6()   asm volatile("s_waitcnt vmcnt(6)" ::: "memory")

  // prologue: tile0 -> buf0 (k=0) full; tile1 -> buf1 (k=64) minus B-ks1
  STAGE_A(0, 0, 0);  STAGE_B(0, 0, 0);  STAGE_A(0, 1, 0);  STAGE_B(0, 1, 0);
  STAGE_A(1, 0, 64); STAGE_B(1, 0, 64); STAGE_A(1, 1, 64);
  VM6(); // buf0 complete; 3 half-tiles in flight (steady P8 state)
  SB0(); BAR();

#pragma unroll 1
  for (int it = 0; it < 8; ++it) {
    const int kk1 = it * 128 + 64;            // tile 2it+1 (its B-ks1, staged at P1)
    const int kk2 = (it * 128 + 128) & 1023;  // tile 2it+2 -> buf0 (wraps harmlessly)
    const int kk3 = (it * 128 + 192) & 1023;  // tile 2it+3 -> buf1
    // P1
    LDA8(0, 0); LDB2(0, 0, 0); STAGE_B(1, 1, kk1);
    SB0(); BAR(); LGKM0();
    __builtin_amdgcn_s_setprio(1); MFMA16(0); __builtin_amdgcn_s_setprio(0);
    SB0(); BAR();
    // P2
    LDB2(0, 0, 1); STAGE_A(0, 0, kk2);
    SB0(); BAR(); LGKM0();
    __builtin_amdgcn_s_setprio(1); MFMA16(1); __builtin_amdgcn_s_setprio(0);
    SB0(); BAR();
    // P3
    LDA8(0, 1); LDB2(0, 1, 0); STAGE_B(0, 0, kk2);
    SB0(); BAR(); LGKM0();
    __builtin_amdgcn_s_setprio(1); MFMA16(0); __builtin_amdgcn_s_setprio(0);
    SB0(); BAR();
    // P4
    LDB2(0, 1, 1); STAGE_A(0, 1, kk2);
    SB0(); BAR(); LGKM0();
    __builtin_amdgcn_s_setprio(1); MFMA16(1); __builtin_amdgcn_s_setprio(0);
    VM6(); // gates buf1 reads (P5-P8): everything issued <= P1 has landed
    SB0(); BAR();
    // P5
    LDA8(1, 0); LDB2(1, 0, 0); STAGE_B(0, 1, kk2);
    SB0(); BAR(); LGKM0();
    __builtin_amdgcn_s_setprio(1); MFMA16(0); __builtin_amdgcn_s_setprio(0);
    SB0(); BAR();
    // P6
    LDB2(1, 0, 1); STAGE_A(1, 0, kk3);
    SB0(); BAR(); LGKM0();
    __builtin_amdgcn_s_setprio(1); MFMA16(1); __builtin_amdgcn_s_setprio(0);
    SB0(); BAR();
    // P7
    LDA8(1, 1); LDB2(1, 1, 0); STAGE_B(1, 0, kk3);
    SB0(); BAR(); LGKM0();
    __builtin_amdgcn_s_setprio(1); MFMA16(0); __builtin_amdgcn_s_setprio(0);
    SB0(); BAR();
    // P8
    LDB2(1, 1, 1); STAGE_A(1, 1, kk3);
    SB0(); BAR(); LGKM0();
    __builtin_amdgcn_s_setprio(1); MFMA16(1); __builtin_amdgcn_s_setprio(0);
    VM6(); // gates buf0 reads (next P1-P4): everything issued <= P5 has landed
    SB0(); BAR();
  }
  asm volatile("s_waitcnt vmcnt(0)" ::: "memory");
  __syncthreads();

  // ---------------- epilogues ----------------
  const int gcol0 = n0 + wn * 64 + fr;      // true col, + j*16
  const int scol  = n0 + wn * 64 + fr * 4;  // permuted stored col base

  if constexpr (EPI == 0) {
    // proj: +bias, permuted bf16 store, row-sumsq (of ROUNDED values) atomics
#pragma unroll
    for (int i = 0; i < 8; ++i)
#pragma unroll
      for (int r = 0; r < 4; ++r) {
        const int gm = m0 + wm * 128 + i * 16 + kq * 4 + r;
        float racc = 0.f;
        ushort4 o; unsigned short* op = (unsigned short*)&o;
#pragma unroll
        for (int j = 0; j < 4; ++j) {
          float e = acc[i][j][r] + bias[gcol0 + j * 16];
          unsigned short eb = f2bf(e);
          op[j] = eb;
          float ev = bf2f(eb);
          racc += ev * ev;
        }
        *(ushort4*)(Cb + (size_t)gm * DIM + scol) = o;
        racc += __shfl_xor(racc, 1, 64);
        racc += __shfl_xor(racc, 2, 64);
        racc += __shfl_xor(racc, 4, 64);
        racc += __shfl_xor(racc, 8, 64);
        if (fr == 0) atomicAdd(&red[gm], racc);
      }
  } else if constexpr (EPI == 1) {
    // score: E = exp(-sqrt(max(sqs+sqt-2c,0))/T), permuted bf16 store, row sums
    const float invT = 1.0f / tempPtr[0];
#pragma unroll
    for (int i = 0; i < 8; ++i)
#pragma unroll
      for (int r = 0; r < 4; ++r) {
        const int gm = m0 + wm * 128 + i * 16 + kq * 4 + r;
        const float si = sqs[gm];
        float racc = 0.f;
        ushort4 o; unsigned short* op = (unsigned short*)&o;
#pragma unroll
        for (int j = 0; j < 4; ++j) {
          float d2 = si + sqt[gcol0 + j * 16] - 2.0f * acc[i][j][r];
          float c = sqrtf(fmaxf(d2, 0.0f));
          unsigned short eb = f2bf(__expf(-c * invT));
          op[j] = eb;
          racc += bf2f(eb);
        }
        *(ushort4*)(Eb + (size_t)gm * NTGT + scol) = o;
        racc += __shfl_xor(racc, 1, 64);
        racc += __shfl_xor(racc, 2, 64);
        racc += __shfl_xor(racc, 4, 64);
        racc += __shfl_xor(racc, 8, 64);
        if (fr == 0) atomicAdd(&red[gm], racc);
      }
  } else {
    // split-K PV: fp32 partials, permuted float4 stores
    float* Pz = Cf + (size_t)blockIdx.z * NSRC * DIM;
#pragma unroll
    for (int i = 0; i < 8; ++i)
#pragma unroll
      for (int r = 0; r < 4; ++r) {
        const int gm = m0 + wm * 128 + i * 16 + kq * 4 + r;
        float4 v = make_float4(acc[i][0][r], acc[i][1][r], acc[i][2][r], acc[i][3][r]);
        *(float4*)(Pz + (size_t)gm * DIM + scol) = v;
      }
  }
#undef STAGE_A
#undef STAGE_B
#undef LDA8
#undef LDB2
#undef MFMA16
#undef BAR
#undef SB0
#undef LGKM0
#undef VM6
}

// ---------------- launch ----------------
extern "C" void kernel_launch(void* const* d_in, const int* in_sizes, int n_in,
                              void* d_out, int out_size, void* d_ws, size_t ws_size,
                              hipStream_t stream) {
  const float* source = (const float*)d_in[0];
  const float* target = (const float*)d_in[1];
  const float* W_src  = (const float*)d_in[2];
  const float* b_src  = (const float*)d_in[3];
  const float* W_tgt  = (const float*)d_in[4];
  const float* b_tgt  = (const float*)d_in[5];
  const float* temp   = (const float*)d_in[6];

  float* out     = (float*)d_out;
  float* aligned = out;                         // [NSRC][DIM]
  float* Kout    = out + (size_t)NSRC * DIM;    // final K; staging for split-K partials
  float* parts   = Kout;                        // 4 x [NSRC][DIM] fp32 = exactly 64 MB

  char* ws = (char*)d_ws;
  unsigned short* src_b  = (unsigned short*)(ws + 0);
  unsigned short* tgt_b  = (unsigned short*)(ws + 8388608);
  unsigned short* Wsrc_b = (unsigned short*)(ws + 16777216);
  unsigned short* Wtgt_b = (unsigned short*)(ws + 18874368);
  unsigned short* sp_b   = (unsigned short*)(ws + 20971520);
  unsigned short* tp_b   = (unsigned short*)(ws + 29360128);
  unsigned short* tgtT_b = (unsigned short*)(ws + 37748736);
  unsigned short* E_b    = (unsigned short*)(ws + 46137344); // 32 MB
  float* sq_s  = (float*)(ws + 79691776);                    // 16 KB
  float* sq_t  = (float*)(ws + 79708160);                    // 16 KB
  float* rsums = (float*)(ws + 79724544);                    // 16 KB

  // 0) zero sq_s, sq_t, rsums (contiguous 48 KB)
  hipMemsetAsync(sq_s, 0, 3 * NSRC * sizeof(float), stream);

  // 1) conversions + permuted target transpose
  k_convert_all<<<10240, 256, 0, stream>>>(source, target, W_src, W_tgt,
                                           src_b, tgt_b, Wsrc_b, Wtgt_b);
  k_transpose_bf16<<<dim3(DIM / 32, NTGT / 32), dim3(32, 8), 0, stream>>>(target, tgtT_b, NTGT, DIM);

  // 2) both projections (z selects problem); outputs permuted in DIM; row-sumsq fused
  k_tile256<0, DIM><<<dim3(DIM / 256, NSRC / 256, 2), 512, 0, stream>>>(
      src_b, Wsrc_b, tgt_b, Wtgt_b, b_src, b_tgt, sp_b, tp_b,
      nullptr, nullptr, nullptr, nullptr, nullptr, sq_s, sq_t);

  // 3) score: E bf16 (permuted in NTGT) -> ws, row sums -> rsums
  k_tile256<1, DIM><<<dim3(NTGT / 256, NSRC / 256, 1), 512, 0, stream>>>(
      sp_b, tp_b, nullptr, nullptr, nullptr, nullptr, nullptr, nullptr,
      E_b, nullptr, sq_s, sq_t, temp, rsums, nullptr);

  // 4) E @ target: split-K x4 (chunk=1024), permuted float4 partials into d_out K region
  k_tile256<3, NTGT><<<dim3(DIM / 256, NSRC / 256, 4), 512, 0, stream>>>(
      E_b, tgtT_b, nullptr, nullptr, nullptr, nullptr, nullptr, nullptr,
      nullptr, parts, nullptr, nullptr, nullptr, nullptr, nullptr);

  // 5) finalize: aligned first (reads parts), then K (overwrites parts region)
  k_finalize_aligned<<<4096, 256, 0, stream>>>(parts, aligned, rsums);
  k_finalize_K<<<8192, 256, 0, stream>>>(E_b, Kout, rsums);
}

// Round 5
// 276.744 us; speedup vs baseline: 1.1365x; 1.0125x over previous
//
#include <hip/hip_runtime.h>
#include <stdint.h>

#define DIM  1024
#define NSRC 4096
#define NTGT 4096

typedef __bf16 bf16_t;
typedef bf16_t bf16x8 __attribute__((ext_vector_type(8)));
typedef float  fx4    __attribute__((ext_vector_type(4)));

static __device__ __forceinline__ unsigned short f2bf(float f) {
  union { float f; uint32_t u; } v; v.f = f;
  return (unsigned short)((v.u + 0x7FFFu + ((v.u >> 16) & 1u)) >> 16);
}
static __device__ __forceinline__ float bf2f(unsigned short h) {
  union { uint32_t u; float f; } v; v.u = ((uint32_t)h) << 16;
  return v.f;
}

// async global->LDS, 16B per lane; lds dest is wave-uniform base + lane*16
static __device__ __forceinline__ void gl_lds16(const unsigned short* g, unsigned short* l) {
  __builtin_amdgcn_global_load_lds(
      (__attribute__((address_space(1))) const void*)g,
      (__attribute__((address_space(3))) void*)l, 16, 0, 0);
}

typedef const __attribute__((address_space(3))) unsigned short* lds3p;

// inline-asm ds_read_b128: invisible to the compiler's LDS-DMA hazard pass, so it
// cannot insert conservative vmcnt(0) waits before fragment loads. RAW vs staging
// is enforced by the explicit vmcnt/lgkmcnt ledger + pinned barriers below.
template <int IMM>
static __device__ __forceinline__ bf16x8 dsr128(lds3p p) {
  bf16x8 r;
  asm volatile("ds_read_b128 %0, %1 offset:%2" : "=v"(r) : "v"(p), "n"(IMM));
  return r;
}

// Permutation within each 64-element block: stored s holds true (s>>2)+16*(s&3).
// Inverse (true c comes from stored): p(c) = (c&15)*4 + (c>>4).

// ---------------- fused fp32->bf16 conversion of all four inputs ----------------
__global__ void k_convert_all(const float* __restrict__ s, const float* __restrict__ t,
                              const float* __restrict__ w0, const float* __restrict__ w1,
                              unsigned short* __restrict__ sb, unsigned short* __restrict__ tb,
                              unsigned short* __restrict__ wb0, unsigned short* __restrict__ wb1) {
  int b = blockIdx.x;
  const float* in; unsigned short* out; int idx;
  if (b < 4096)      { in = s;  out = sb;  idx = b * 256 + threadIdx.x; }
  else if (b < 8192) { in = t;  out = tb;  idx = (b - 4096) * 256 + threadIdx.x; }
  else if (b < 9216) { in = w0; out = wb0; idx = (b - 8192) * 256 + threadIdx.x; }
  else               { in = w1; out = wb1; idx = (b - 9216) * 256 + threadIdx.x; }
  float4 v = ((const float4*)in)[idx];
  ushort4 o;
  o.x = f2bf(v.x); o.y = f2bf(v.y); o.z = f2bf(v.z); o.w = f2bf(v.w);
  ((ushort4*)out)[idx] = o;
}

// transpose fp32 target [R=NTGT][C=DIM] -> bf16 tgtT_b[n][s] = target[true(s)][n]
__global__ void k_transpose_bf16(const float* __restrict__ in, unsigned short* __restrict__ out,
                                 int R, int C) {
  __shared__ unsigned short tile[32][33];
  int c0 = blockIdx.x * 32, r0 = blockIdx.y * 32;
  int tx = threadIdx.x, ty = threadIdx.y; // 32 x 8
  for (int i = ty; i < 32; i += 8) {
    int row = r0 + i;
    int p = row & 63;
    int tr = (row & ~63) | ((p >> 2) | ((p & 3) << 4)); // true(row)
    tile[i][tx] = f2bf(in[(size_t)tr * C + c0 + tx]);
  }
  __syncthreads();
  for (int i = ty; i < 32; i += 8)
    out[(size_t)(c0 + i) * R + r0 + tx] = tile[tx][i];
}

// ---------------- finalize ----------------
// aligned = sum(P[0..3]) / rs   (z=4 split-K partials)
__global__ void k_finalize_aligned(const float* __restrict__ P, float* __restrict__ aligned,
                                   const float* __restrict__ rs) {
  const int b = blockIdx.x;
  const int lane = threadIdx.x & 63, w = threadIdx.x >> 6;
  const int src = ((lane & 15) << 2) | (lane >> 4);
  const size_t stride = (size_t)NSRC * DIM;
#pragma unroll
  for (int it = 0; it < 4; ++it) {
    int idx = b * 16 + w * 4 + it;   // 64-block index; 16 per row of DIM
    size_t base = (size_t)idx * 64;
    float r = 1.0f / rs[idx >> 4];
    float v = (P[base + lane] + P[base + stride + lane] +
               P[base + 2 * stride + lane] + P[base + 3 * stride + lane]) * r;
    aligned[base + lane] = __shfl(v, src, 64);
  }
}

// K = bf2f(Eb)/rs (un-permuted)
__global__ void k_finalize_K(const unsigned short* __restrict__ Eb, float* __restrict__ Kf,
                             const float* __restrict__ rs) {
  const int b = blockIdx.x;
  const int lane = threadIdx.x & 63, w = threadIdx.x >> 6;
  const int src = ((lane & 15) << 2) | (lane >> 4);
#pragma unroll
  for (int it = 0; it < 8; ++it) {
    int idx = b * 32 + w * 8 + it;  // 64-block index; 64 per row of NTGT
    size_t base = (size_t)idx * 64;
    float r = 1.0f / rs[idx >> 6];
    float v = bf2f(Eb[base + lane]) * r;
    Kf[base + lane] = __shfl(v, src, 64);
  }
}

// ---------------- 256x256 8-phase GEMM template (T2+T3+T4+T5) ----------------
// NT bf16: A [M rows][LDK k], B [N rows][LDK k], both row-major K-contiguous,
// both with the SAME K-permutation (dot products invariant).
// K-chunk is always 1024 (8 iterations of the verified 8-phase loop).
// LDS: [buf(2)][ksb(2)][stripe(16)][16 rows][32 k] bf16, st_16x32 XOR-swizzle
// applied on the GLOBAL source col (gl_lds dest is linear) and on ds_read addr.
// Fragment loads are inline-asm ds_read_b128 (see dsr128): keeps the counted
// vmcnt(6) pipeline intact (compiler would otherwise insert vmcnt(0) hazards).
// EPI 0: proj: z selects (A,B,bias,out,red); +bias, permuted bf16 out, row-sumsq atomics
// EPI 1: score: E=exp(-sqrt(max(sqs+sqt-2c,0))/T) permuted bf16 out, row-sum atomics
// EPI 3: split-K PV: z = k-chunk; fp32 partial float4 stores (permuted cols)
template <int EPI, int LDK>
__global__ void __launch_bounds__(512, 2)
k_tile256(const unsigned short* __restrict__ A0, const unsigned short* __restrict__ B0,
          const unsigned short* __restrict__ A1, const unsigned short* __restrict__ B1,
          const float* __restrict__ bias0, const float* __restrict__ bias1,
          unsigned short* __restrict__ Cb0, unsigned short* __restrict__ Cb1,
          unsigned short* __restrict__ Eb, float* __restrict__ Cf,
          const float* __restrict__ sqs, const float* __restrict__ sqt,
          const float* __restrict__ tempPtr,
          float* __restrict__ red0, float* __restrict__ red1) {
  __shared__ unsigned short ldsA[32768]; // 64 KB
  __shared__ unsigned short ldsB[32768]; // 64 KB

  const unsigned short* A = A0;
  const unsigned short* B = B0;
  const float* bias = bias0;
  unsigned short* Cb = Cb0;
  float* red = red0;
  if constexpr (EPI == 0) {
    if (blockIdx.z) { A = A1; B = B1; bias = bias1; Cb = Cb1; red = red1; }
  }
  if constexpr (EPI == 3) { A += blockIdx.z * 1024; B += blockIdx.z * 1024; }

  const int tid = threadIdx.x;
  const int lane = tid & 63, w = tid >> 6;   // 8 waves
  const int wm = w >> 2, wn = w & 3;         // 2 x 4
  const int fr = lane & 15, kq = lane >> 4;
  const int m0 = blockIdx.y * 256, n0 = blockIdx.x * 256;

  // stage: wave w instr n covers stripe (n*8+w); lane -> (row-in-stripe, swizzled k-col)
  const int rin = lane >> 2;
  const int cs  = ((lane & 3) * 8) ^ ((lane >> 5) ? 16 : 0); // inverse-swizzled source col
  const size_t aoff0 = (size_t)(m0 + w * 16 + rin) * LDK + cs;
  const size_t aoff1 = (size_t)(m0 + (8 + w) * 16 + rin) * LDK + cs;
  const size_t boff0 = (size_t)(n0 + w * 16 + rin) * LDK + cs;
  const size_t boff1 = (size_t)(n0 + (8 + w) * 16 + rin) * LDK + cs;

  // ds_read per-lane offset (shorts), swizzled
  const int roA = fr * 32 + ((kq * 8) ^ ((fr & 8) ? 16 : 0));
  // per-lane AS3 base pointers; per-read delta folded into the 16-bit offset: imm
  const lds3p baseA = (lds3p)ldsA + wm * 4096 + roA; // wm*8 rows * 512 shorts
  const lds3p baseB = (lds3p)ldsB + wn * 2048 + roA; // wn*4 rows * 512 shorts

#define STAGE_A(buf, ksb, kk) do { \
    gl_lds16(A + aoff0 + (kk) + (ksb) * 32, ldsA + (buf) * 16384 + (ksb) * 8192 + w * 512); \
    gl_lds16(A + aoff1 + (kk) + (ksb) * 32, ldsA + (buf) * 16384 + (ksb) * 8192 + (8 + w) * 512); \
  } while (0)
#define STAGE_B(buf, ksb, kk) do { \
    gl_lds16(B + boff0 + (kk) + (ksb) * 32, ldsB + (buf) * 16384 + (ksb) * 8192 + w * 512); \
    gl_lds16(B + boff1 + (kk) + (ksb) * 32, ldsB + (buf) * 16384 + (ksb) * 8192 + (8 + w) * 512); \
  } while (0)

  const fx4 fz = {0.f, 0.f, 0.f, 0.f};
  fx4 acc[8][4];
#pragma unroll
  for (int i = 0; i < 8; ++i)
#pragma unroll
    for (int j = 0; j < 4; ++j) acc[i][j] = fz;

  bf16x8 a[8], b0v, b1v;

  // byte-offset immediates: buf*32768 + ks*16384 + row_in_group*1024
#define LDA1(buf, ks, i) a[i] = dsr128<(buf) * 32768 + (ks) * 16384 + (i) * 1024>(baseA)
#define LDA8(buf, ks) do { \
    LDA1(buf, ks, 0); LDA1(buf, ks, 1); LDA1(buf, ks, 2); LDA1(buf, ks, 3); \
    LDA1(buf, ks, 4); LDA1(buf, ks, 5); LDA1(buf, ks, 6); LDA1(buf, ks, 7); \
  } while (0)
#define LDB2(buf, ks, jh) do { \
    b0v = dsr128<(buf) * 32768 + (ks) * 16384 + (jh) * 2048>(baseB); \
    b1v = dsr128<(buf) * 32768 + (ks) * 16384 + (jh) * 2048 + 1024>(baseB); \
  } while (0)
#define MFMA16(jh) do { _Pragma("unroll") \
    for (int i = 0; i < 8; ++i) { \
      acc[i][(jh) * 2]     = __builtin_amdgcn_mfma_f32_16x16x32_bf16(a[i], b0v, acc[i][(jh) * 2], 0, 0, 0); \
      acc[i][(jh) * 2 + 1] = __builtin_amdgcn_mfma_f32_16x16x32_bf16(a[i], b1v, acc[i][(jh) * 2 + 1], 0, 0, 0); \
    } } while (0)
#define SB0()   __builtin_amdgcn_sched_barrier(0)
#define BARS()  do { SB0(); __builtin_amdgcn_s_barrier(); SB0(); } while (0)
#define LGKM0() do { asm volatile("s_waitcnt lgkmcnt(0)" ::: "memory"); SB0(); } while (0)
#define VM6()   asm volatile("s_waitcnt vmcnt(6)" ::: "memory")

  // prologue: tile0 -> buf0 (k=0) full; tile1 -> buf1 (k=64) minus B-ks1
  STAGE_A(0, 0, 0);  STAGE_B(0, 0, 0);  STAGE_A(0, 1, 0);  STAGE_B(0, 1, 0);
  STAGE_A(1, 0, 64); STAGE_B(1, 0, 64); STAGE_A(1, 1, 64);
  VM6(); // 14 issued, wait to 6 -> the 8 oldest (all of buf0) have landed
  BARS();

#pragma unroll 1
  for (int it = 0; it < 8; ++it) {
    const int kk1 = it * 128 + 64;            // tile 2it+1 (its B-ks1, staged at P1)
    const int kk2 = (it * 128 + 128) & 1023;  // tile 2it+2 -> buf0 (wraps harmlessly)
    const int kk3 = (it * 128 + 192) & 1023;  // tile 2it+3 -> buf1
    // P1
    LDA8(0, 0); LDB2(0, 0, 0); STAGE_B(1, 1, kk1);
    BARS(); LGKM0();
    __builtin_amdgcn_s_setprio(1); MFMA16(0); __builtin_amdgcn_s_setprio(0);
    BARS();
    // P2
    LDB2(0, 0, 1); STAGE_A(0, 0, kk2);
    BARS(); LGKM0();
    __builtin_amdgcn_s_setprio(1); MFMA16(1); __builtin_amdgcn_s_setprio(0);
    BARS();
    // P3
    LDA8(0, 1); LDB2(0, 1, 0); STAGE_B(0, 0, kk2);
    BARS(); LGKM0();
    __builtin_amdgcn_s_setprio(1); MFMA16(0); __builtin_amdgcn_s_setprio(0);
    BARS();
    // P4
    LDB2(0, 1, 1); STAGE_A(0, 1, kk2);
    BARS(); LGKM0();
    __builtin_amdgcn_s_setprio(1); MFMA16(1); __builtin_amdgcn_s_setprio(0);
    VM6(); // gates buf1 reads (P5-P8): everything issued <= P1 has landed
    BARS();
    // P5
    LDA8(1, 0); LDB2(1, 0, 0); STAGE_B(0, 1, kk2);
    BARS(); LGKM0();
    __builtin_amdgcn_s_setprio(1); MFMA16(0); __builtin_amdgcn_s_setprio(0);
    BARS();
    // P6
    LDB2(1, 0, 1); STAGE_A(1, 0, kk3);
    BARS(); LGKM0();
    __builtin_amdgcn_s_setprio(1); MFMA16(1); __builtin_amdgcn_s_setprio(0);
    BARS();
    // P7
    LDA8(1, 1); LDB2(1, 1, 0); STAGE_B(1, 0, kk3);
    BARS(); LGKM0();
    __builtin_amdgcn_s_setprio(1); MFMA16(0); __builtin_amdgcn_s_setprio(0);
    BARS();
    // P8
    LDB2(1, 1, 1); STAGE_A(1, 1, kk3);
    BARS(); LGKM0();
    __builtin_amdgcn_s_setprio(1); MFMA16(1); __builtin_amdgcn_s_setprio(0);
    VM6(); // gates buf0 reads (next P1-P4): everything issued <= P5 has landed
    BARS();
  }
  asm volatile("s_waitcnt vmcnt(0)" ::: "memory");
  __syncthreads();

  // ---------------- epilogues ----------------
  const int gcol0 = n0 + wn * 64 + fr;      // true col, + j*16
  const int scol  = n0 + wn * 64 + fr * 4;  // permuted stored col base

  if constexpr (EPI == 0) {
    // proj: +bias, permuted bf16 store, row-sumsq (of ROUNDED values) atomics
#pragma unroll
    for (int i = 0; i < 8; ++i)
#pragma unroll
      for (int r = 0; r < 4; ++r) {
        const int gm = m0 + wm * 128 + i * 16 + kq * 4 + r;
        float racc = 0.f;
        ushort4 o; unsigned short* op = (unsigned short*)&o;
#pragma unroll
        for (int j = 0; j < 4; ++j) {
          float e = acc[i][j][r] + bias[gcol0 + j * 16];
          unsigned short eb = f2bf(e);
          op[j] = eb;
          float ev = bf2f(eb);
          racc += ev * ev;
        }
        *(ushort4*)(Cb + (size_t)gm * DIM + scol) = o;
        racc += __shfl_xor(racc, 1, 64);
        racc += __shfl_xor(racc, 2, 64);
        racc += __shfl_xor(racc, 4, 64);
        racc += __shfl_xor(racc, 8, 64);
        if (fr == 0) atomicAdd(&red[gm], racc);
      }
  } else if constexpr (EPI == 1) {
    // score: E = exp(-sqrt(max(sqs+sqt-2c,0))/T), permuted bf16 store, row sums
    const float invT = 1.0f / tempPtr[0];
#pragma unroll
    for (int i = 0; i < 8; ++i)
#pragma unroll
      for (int r = 0; r < 4; ++r) {
        const int gm = m0 + wm * 128 + i * 16 + kq * 4 + r;
        const float si = sqs[gm];
        float racc = 0.f;
        ushort4 o; unsigned short* op = (unsigned short*)&o;
#pragma unroll
        for (int j = 0; j < 4; ++j) {
          float d2 = si + sqt[gcol0 + j * 16] - 2.0f * acc[i][j][r];
          float c = sqrtf(fmaxf(d2, 0.0f));
          unsigned short eb = f2bf(__expf(-c * invT));
          op[j] = eb;
          racc += bf2f(eb);
        }
        *(ushort4*)(Eb + (size_t)gm * NTGT + scol) = o;
        racc += __shfl_xor(racc, 1, 64);
        racc += __shfl_xor(racc, 2, 64);
        racc += __shfl_xor(racc, 4, 64);
        racc += __shfl_xor(racc, 8, 64);
        if (fr == 0) atomicAdd(&red[gm], racc);
      }
  } else {
    // split-K PV: fp32 partials, permuted float4 stores
    float* Pz = Cf + (size_t)blockIdx.z * NSRC * DIM;
#pragma unroll
    for (int i = 0; i < 8; ++i)
#pragma unroll
      for (int r = 0; r < 4; ++r) {
        const int gm = m0 + wm * 128 + i * 16 + kq * 4 + r;
        float4 v = make_float4(acc[i][0][r], acc[i][1][r], acc[i][2][r], acc[i][3][r]);
        *(float4*)(Pz + (size_t)gm * DIM + scol) = v;
      }
  }
#undef STAGE_A
#undef STAGE_B
#undef LDA1
#undef LDA8
#undef LDB2
#undef MFMA16
#undef SB0
#undef BARS
#undef LGKM0
#undef VM6
}

// ---------------- launch ----------------
extern "C" void kernel_launch(void* const* d_in, const int* in_sizes, int n_in,
                              void* d_out, int out_size, void* d_ws, size_t ws_size,
                              hipStream_t stream) {
  const float* source = (const float*)d_in[0];
  const float* target = (const float*)d_in[1];
  const float* W_src  = (const float*)d_in[2];
  const float* b_src  = (const float*)d_in[3];
  const float* W_tgt  = (const float*)d_in[4];
  const float* b_tgt  = (const float*)d_in[5];
  const float* temp   = (const float*)d_in[6];

  float* out     = (float*)d_out;
  float* aligned = out;                         // [NSRC][DIM]
  float* Kout    = out + (size_t)NSRC * DIM;    // final K; staging for split-K partials
  float* parts   = Kout;                        // 4 x [NSRC][DIM] fp32 = exactly 64 MB

  char* ws = (char*)d_ws;
  unsigned short* src_b  = (unsigned short*)(ws + 0);
  unsigned short* tgt_b  = (unsigned short*)(ws + 8388608);
  unsigned short* Wsrc_b = (unsigned short*)(ws + 16777216);
  unsigned short* Wtgt_b = (unsigned short*)(ws + 18874368);
  unsigned short* sp_b   = (unsigned short*)(ws + 20971520);
  unsigned short* tp_b   = (unsigned short*)(ws + 29360128);
  unsigned short* tgtT_b = (unsigned short*)(ws + 37748736);
  unsigned short* E_b    = (unsigned short*)(ws + 46137344); // 32 MB
  float* sq_s  = (float*)(ws + 79691776);                    // 16 KB
  float* sq_t  = (float*)(ws + 79708160);                    // 16 KB
  float* rsums = (float*)(ws + 79724544);                    // 16 KB

  // 0) zero sq_s, sq_t, rsums (contiguous 48 KB)
  hipMemsetAsync(sq_s, 0, 3 * NSRC * sizeof(float), stream);

  // 1) conversions + permuted target transpose
  k_convert_all<<<10240, 256, 0, stream>>>(source, target, W_src, W_tgt,
                                           src_b, tgt_b, Wsrc_b, Wtgt_b);
  k_transpose_bf16<<<dim3(DIM / 32, NTGT / 32), dim3(32, 8), 0, stream>>>(target, tgtT_b, NTGT, DIM);

  // 2) both projections (z selects problem); outputs permuted in DIM; row-sumsq fused
  k_tile256<0, DIM><<<dim3(DIM / 256, NSRC / 256, 2), 512, 0, stream>>>(
      src_b, Wsrc_b, tgt_b, Wtgt_b, b_src, b_tgt, sp_b, tp_b,
      nullptr, nullptr, nullptr, nullptr, nullptr, sq_s, sq_t);

  // 3) score: E bf16 (permuted in NTGT) -> ws, row sums -> rsums
  k_tile256<1, DIM><<<dim3(NTGT / 256, NSRC / 256, 1), 512, 0, stream>>>(
      sp_b, tp_b, nullptr, nullptr, nullptr, nullptr, nullptr, nullptr,
      E_b, nullptr, sq_s, sq_t, temp, rsums, nullptr);

  // 4) E @ target: split-K x4 (chunk=1024), permuted float4 partials into d_out K region
  k_tile256<3, NTGT><<<dim3(DIM / 256, NSRC / 256, 4), 512, 0, stream>>>(
      E_b, tgtT_b, nullptr, nullptr, nullptr, nullptr, nullptr, nullptr,
      nullptr, parts, nullptr, nullptr, nullptr, nullptr, nullptr);

  // 5) finalize: aligned first (reads parts), then K (overwrites parts region)
  k_finalize_aligned<<<4096, 256, 0, stream>>>(parts, aligned, rsums);
  k_finalize_K<<<8192, 256, 0, stream>>>(E_b, Kout, rsums);
}

// Round 6
// 276.690 us; speedup vs baseline: 1.1367x; 1.0002x over previous
//
#include <hip/hip_runtime.h>
#include <stdint.h>

#define DIM  1024
#define NSRC 4096
#define NTGT 4096

typedef __bf16 bf16_t;
typedef bf16_t bf16x8 __attribute__((ext_vector_type(8)));
typedef float  fx4    __attribute__((ext_vector_type(4)));

static __device__ __forceinline__ unsigned short f2bf(float f) {
  union { float f; uint32_t u; } v; v.f = f;
  return (unsigned short)((v.u + 0x7FFFu + ((v.u >> 16) & 1u)) >> 16);
}
static __device__ __forceinline__ float bf2f(unsigned short h) {
  union { uint32_t u; float f; } v; v.u = ((uint32_t)h) << 16;
  return v.f;
}

// async global->LDS, 16B per lane; lds dest is wave-uniform base + lane*16
static __device__ __forceinline__ void gl_lds16(const unsigned short* g, unsigned short* l) {
  __builtin_amdgcn_global_load_lds(
      (__attribute__((address_space(1))) const void*)g,
      (__attribute__((address_space(3))) void*)l, 16, 0, 0);
}

typedef const __attribute__((address_space(3))) unsigned short* lds3p;

// inline-asm ds_read_b128 with compile-time offset immediate.
template <int IMM>
static __device__ __forceinline__ bf16x8 dsr128(lds3p p) {
  bf16x8 r;
  asm volatile("ds_read_b128 %0, %1 offset:%2" : "=v"(r) : "v"(p), "n"(IMM));
  return r;
}

// Permutation within each 64-element block: stored s holds true (s>>2)+16*(s&3).
// Inverse (true c comes from stored): p(c) = (c&15)*4 + (c>>4).

// ---------------- fused fp32->bf16 conversion of all four inputs ----------------
__global__ void k_convert_all(const float* __restrict__ s, const float* __restrict__ t,
                              const float* __restrict__ w0, const float* __restrict__ w1,
                              unsigned short* __restrict__ sb, unsigned short* __restrict__ tb,
                              unsigned short* __restrict__ wb0, unsigned short* __restrict__ wb1) {
  int b = blockIdx.x;
  const float* in; unsigned short* out; int idx;
  if (b < 4096)      { in = s;  out = sb;  idx = b * 256 + threadIdx.x; }
  else if (b < 8192) { in = t;  out = tb;  idx = (b - 4096) * 256 + threadIdx.x; }
  else if (b < 9216) { in = w0; out = wb0; idx = (b - 8192) * 256 + threadIdx.x; }
  else               { in = w1; out = wb1; idx = (b - 9216) * 256 + threadIdx.x; }
  float4 v = ((const float4*)in)[idx];
  ushort4 o;
  o.x = f2bf(v.x); o.y = f2bf(v.y); o.z = f2bf(v.z); o.w = f2bf(v.w);
  ((ushort4*)out)[idx] = o;
}

// transpose fp32 target [R=NTGT][C=DIM] -> bf16 tgtT_b[n][s] = target[true(s)][n]
__global__ void k_transpose_bf16(const float* __restrict__ in, unsigned short* __restrict__ out,
                                 int R, int C) {
  __shared__ unsigned short tile[32][33];
  int c0 = blockIdx.x * 32, r0 = blockIdx.y * 32;
  int tx = threadIdx.x, ty = threadIdx.y; // 32 x 8
  for (int i = ty; i < 32; i += 8) {
    int row = r0 + i;
    int p = row & 63;
    int tr = (row & ~63) | ((p >> 2) | ((p & 3) << 4)); // true(row)
    tile[i][tx] = f2bf(in[(size_t)tr * C + c0 + tx]);
  }
  __syncthreads();
  for (int i = ty; i < 32; i += 8)
    out[(size_t)(c0 + i) * R + r0 + tx] = tile[tx][i];
}

// ---------------- finalize ----------------
// aligned = sum(P[0..3]) / rs   (z=4 split-K partials)
__global__ void k_finalize_aligned(const float* __restrict__ P, float* __restrict__ aligned,
                                   const float* __restrict__ rs) {
  const int b = blockIdx.x;
  const int lane = threadIdx.x & 63, w = threadIdx.x >> 6;
  const int src = ((lane & 15) << 2) | (lane >> 4);
  const size_t stride = (size_t)NSRC * DIM;
#pragma unroll
  for (int it = 0; it < 4; ++it) {
    int idx = b * 16 + w * 4 + it;   // 64-block index; 16 per row of DIM
    size_t base = (size_t)idx * 64;
    float r = 1.0f / rs[idx >> 4];
    float v = (P[base + lane] + P[base + stride + lane] +
               P[base + 2 * stride + lane] + P[base + 3 * stride + lane]) * r;
    aligned[base + lane] = __shfl(v, src, 64);
  }
}

// K = bf2f(Eb)/rs (un-permuted)
__global__ void k_finalize_K(const unsigned short* __restrict__ Eb, float* __restrict__ Kf,
                             const float* __restrict__ rs) {
  const int b = blockIdx.x;
  const int lane = threadIdx.x & 63, w = threadIdx.x >> 6;
  const int src = ((lane & 15) << 2) | (lane >> 4);
#pragma unroll
  for (int it = 0; it < 8; ++it) {
    int idx = b * 32 + w * 8 + it;  // 64-block index; 64 per row of NTGT
    size_t base = (size_t)idx * 64;
    float r = 1.0f / rs[idx >> 6];
    float v = bf2f(Eb[base + lane]) * r;
    Kf[base + lane] = __shfl(v, src, 64);
  }
}

// ---------------- 256x256 4-fat-phase GEMM template ----------------
// NT bf16: A [M rows][LDK k], B [N rows][LDK k], K-chunk always 1024.
// 4 phases/iter (2 K-tiles of 64): per phase 12 ds_read + 1 full-slot stage
// (A:2 + B:2 gl_lds) + 32 MFMA split by lgkmcnt(2)/lgkmcnt(0) so tail reads
// drain under the first MFMA cluster. Barrier events halved vs 8-phase.
// Ledger: stage in phase P targets the slot read in phase P-1 (>=1 barrier +
// full lgkm drain between -> WAR safe). vmcnt(4) at end of PH2 (gates buf1)
// and PH4 (gates buf0): outstanding = 1 phase x 4 loads.
// LDS st_16x32 XOR-swizzle on global source col + ds_read addr (bank-conflict 0).
// EPI 0: proj +bias, permuted bf16 out, row-sumsq atomics (z selects problem)
// EPI 1: score E=exp(-sqrt(max(sqs+sqt-2c,0))/T), permuted bf16 out, row sums
// EPI 3: split-K PV (z = k-chunk), fp32 partial float4 stores (permuted cols)
template <int EPI, int LDK>
__global__ void __launch_bounds__(512, 2)
k_tile256(const unsigned short* __restrict__ A0, const unsigned short* __restrict__ B0,
          const unsigned short* __restrict__ A1, const unsigned short* __restrict__ B1,
          const float* __restrict__ bias0, const float* __restrict__ bias1,
          unsigned short* __restrict__ Cb0, unsigned short* __restrict__ Cb1,
          unsigned short* __restrict__ Eb, float* __restrict__ Cf,
          const float* __restrict__ sqs, const float* __restrict__ sqt,
          const float* __restrict__ tempPtr,
          float* __restrict__ red0, float* __restrict__ red1) {
  __shared__ unsigned short ldsA[32768]; // 64 KB
  __shared__ unsigned short ldsB[32768]; // 64 KB

  const unsigned short* A = A0;
  const unsigned short* B = B0;
  const float* bias = bias0;
  unsigned short* Cb = Cb0;
  float* red = red0;
  if constexpr (EPI == 0) {
    if (blockIdx.z) { A = A1; B = B1; bias = bias1; Cb = Cb1; red = red1; }
  }
  if constexpr (EPI == 3) { A += blockIdx.z * 1024; B += blockIdx.z * 1024; }

  // XCD-aware bijective swizzle of (x,y): all grids have nwg%8==0.
  int nbx = blockIdx.x, nby = blockIdx.y;
  {
    const int nx = gridDim.x, n = gridDim.x * gridDim.y;
    const int id = nby * nx + nbx;
    const int q = n >> 3;
    const int s = (id & 7) * q + (id >> 3);
    nbx = s % nx; nby = s / nx;
  }

  const int tid = threadIdx.x;
  const int lane = tid & 63, w = tid >> 6;   // 8 waves
  const int wm = w >> 2, wn = w & 3;         // 2 x 4
  const int fr = lane & 15, kq = lane >> 4;
  const int m0 = nby * 256, n0 = nbx * 256;

  // stage: wave w instr n covers stripe (n*8+w); lane -> (row-in-stripe, swizzled k-col)
  const int rin = lane >> 2;
  const int cs  = ((lane & 3) * 8) ^ ((lane >> 5) ? 16 : 0); // inverse-swizzled source col
  const size_t aoff0 = (size_t)(m0 + w * 16 + rin) * LDK + cs;
  const size_t aoff1 = (size_t)(m0 + (8 + w) * 16 + rin) * LDK + cs;
  const size_t boff0 = (size_t)(n0 + w * 16 + rin) * LDK + cs;
  const size_t boff1 = (size_t)(n0 + (8 + w) * 16 + rin) * LDK + cs;

  // ds_read per-lane offset (shorts), swizzled
  const int roA = fr * 32 + ((kq * 8) ^ ((fr & 8) ? 16 : 0));
  const lds3p baseA = (lds3p)ldsA + wm * 4096 + roA; // wm*8 rows * 512 shorts
  const lds3p baseB = (lds3p)ldsB + wn * 2048 + roA; // wn*4 rows * 512 shorts

#define STAGE_A(buf, ksb, kk) do { \
    gl_lds16(A + aoff0 + (kk) + (ksb) * 32, ldsA + (buf) * 16384 + (ksb) * 8192 + w * 512); \
    gl_lds16(A + aoff1 + (kk) + (ksb) * 32, ldsA + (buf) * 16384 + (ksb) * 8192 + (8 + w) * 512); \
  } while (0)
#define STAGE_B(buf, ksb, kk) do { \
    gl_lds16(B + boff0 + (kk) + (ksb) * 32, ldsB + (buf) * 16384 + (ksb) * 8192 + w * 512); \
    gl_lds16(B + boff1 + (kk) + (ksb) * 32, ldsB + (buf) * 16384 + (ksb) * 8192 + (8 + w) * 512); \
  } while (0)

  const fx4 fz = {0.f, 0.f, 0.f, 0.f};
  fx4 acc[8][4];
#pragma unroll
  for (int i = 0; i < 8; ++i)
#pragma unroll
    for (int j = 0; j < 4; ++j) acc[i][j] = fz;

  bf16x8 a[8], b0v, b1v, b2v, b3v;

  // byte-offset immediates: buf*32768 + ks*16384 + row_in_group*1024
#define LDA1(buf, ks, i) a[i] = dsr128<(buf) * 32768 + (ks) * 16384 + (i) * 1024>(baseA)
#define LDA8(buf, ks) do { \
    LDA1(buf, ks, 0); LDA1(buf, ks, 1); LDA1(buf, ks, 2); LDA1(buf, ks, 3); \
    LDA1(buf, ks, 4); LDA1(buf, ks, 5); LDA1(buf, ks, 6); LDA1(buf, ks, 7); \
  } while (0)
#define LDB2(buf, ks, jh, r0, r1) do { \
    r0 = dsr128<(buf) * 32768 + (ks) * 16384 + (jh) * 2048>(baseB); \
    r1 = dsr128<(buf) * 32768 + (ks) * 16384 + (jh) * 2048 + 1024>(baseB); \
  } while (0)
#define MFMA16(jh, r0, r1) do { _Pragma("unroll") \
    for (int i = 0; i < 8; ++i) { \
      acc[i][(jh) * 2]     = __builtin_amdgcn_mfma_f32_16x16x32_bf16(a[i], r0, acc[i][(jh) * 2], 0, 0, 0); \
      acc[i][(jh) * 2 + 1] = __builtin_amdgcn_mfma_f32_16x16x32_bf16(a[i], r1, acc[i][(jh) * 2 + 1], 0, 0, 0); \
    } } while (0)
#define SB0()   __builtin_amdgcn_sched_barrier(0)
#define BARS()  do { SB0(); __builtin_amdgcn_s_barrier(); SB0(); } while (0)
#define LGKM2() do { asm volatile("s_waitcnt lgkmcnt(2)" ::: "memory"); SB0(); } while (0)
#define LGKM0() do { asm volatile("s_waitcnt lgkmcnt(0)" ::: "memory"); SB0(); } while (0)
#define VM4()   asm volatile("s_waitcnt vmcnt(4)" ::: "memory")

  // fat phase: read one 32-K subtile (b-jh0, a0..7, b-jh1 = 12 reads, in-order
  // retire), stage one future slot, then 32 MFMA with split waits.
#define PHASE(buf, ks, sb, sk, kk) do { \
    LDB2(buf, ks, 0, b0v, b1v); LDA8(buf, ks); LDB2(buf, ks, 1, b2v, b3v); \
    STAGE_A(sb, sk, kk); STAGE_B(sb, sk, kk); \
    BARS(); LGKM2(); \
    __builtin_amdgcn_s_setprio(1); \
    MFMA16(0, b0v, b1v); \
    LGKM0(); \
    MFMA16(1, b2v, b3v); \
    __builtin_amdgcn_s_setprio(0); \
  } while (0)

  // prologue: buf0 full (tile0) + buf1 ks0 (tile1 first half) = 12 loads
  STAGE_A(0, 0, 0);  STAGE_B(0, 0, 0);  STAGE_A(0, 1, 0);  STAGE_B(0, 1, 0);
  STAGE_A(1, 0, 64); STAGE_B(1, 0, 64);
  VM4(); // 12 issued, drain to 4 -> the 8 oldest (all of buf0) have landed
  BARS();

#pragma unroll 1
  for (int it = 0; it < 8; ++it) {
    const int kk1 = it * 128 + 64;            // tile 2it+1 base (stage its ks1 at PH1)
    const int kk2 = (it * 128 + 128) & 1023;  // tile 2it+2 -> buf0 (wrap harmless)
    const int kk3 = (it * 128 + 192) & 1023;  // tile 2it+3 -> buf1 ks0
    // PH1: consume buf0/ks0; stage buf1/ks1 <- tile 2it+1 ks1 (slot read prev PH4)
    PHASE(0, 0, 1, 1, kk1);
    BARS();
    // PH2: consume buf0/ks1; stage buf0/ks0 <- tile 2it+2 (slot read PH1)
    PHASE(0, 1, 0, 0, kk2);
    VM4(); // outstanding = PH2's 4 -> everything <= PH1 landed: buf1 complete
    BARS();
    // PH3: consume buf1/ks0; stage buf0/ks1 <- tile 2it+2 ks1 (slot read PH2)
    PHASE(1, 0, 0, 1, kk2);
    BARS();
    // PH4: consume buf1/ks1; stage buf1/ks0 <- tile 2it+3 (slot read PH3)
    PHASE(1, 1, 1, 0, kk3);
    VM4(); // outstanding = PH4's 4 -> everything <= PH3 landed: buf0 complete
    BARS();
  }
  asm volatile("s_waitcnt vmcnt(0)" ::: "memory");
  __syncthreads();

  // ---------------- epilogues ----------------
  const int gcol0 = n0 + wn * 64 + fr;      // true col, + j*16
  const int scol  = n0 + wn * 64 + fr * 4;  // permuted stored col base

  if constexpr (EPI == 0) {
    // proj: +bias, permuted bf16 store, row-sumsq (of ROUNDED values) atomics
#pragma unroll
    for (int i = 0; i < 8; ++i)
#pragma unroll
      for (int r = 0; r < 4; ++r) {
        const int gm = m0 + wm * 128 + i * 16 + kq * 4 + r;
        float racc = 0.f;
        ushort4 o; unsigned short* op = (unsigned short*)&o;
#pragma unroll
        for (int j = 0; j < 4; ++j) {
          float e = acc[i][j][r] + bias[gcol0 + j * 16];
          unsigned short eb = f2bf(e);
          op[j] = eb;
          float ev = bf2f(eb);
          racc += ev * ev;
        }
        *(ushort4*)(Cb + (size_t)gm * DIM + scol) = o;
        racc += __shfl_xor(racc, 1, 64);
        racc += __shfl_xor(racc, 2, 64);
        racc += __shfl_xor(racc, 4, 64);
        racc += __shfl_xor(racc, 8, 64);
        if (fr == 0) atomicAdd(&red[gm], racc);
      }
  } else if constexpr (EPI == 1) {
    // score: E = exp(-sqrt(max(sqs+sqt-2c,0))/T), permuted bf16 store, row sums
    const float invT = 1.0f / tempPtr[0];
#pragma unroll
    for (int i = 0; i < 8; ++i)
#pragma unroll
      for (int r = 0; r < 4; ++r) {
        const int gm = m0 + wm * 128 + i * 16 + kq * 4 + r;
        const float si = sqs[gm];
        float racc = 0.f;
        ushort4 o; unsigned short* op = (unsigned short*)&o;
#pragma unroll
        for (int j = 0; j < 4; ++j) {
          float d2 = si + sqt[gcol0 + j * 16] - 2.0f * acc[i][j][r];
          float c = sqrtf(fmaxf(d2, 0.0f));
          unsigned short eb = f2bf(__expf(-c * invT));
          op[j] = eb;
          racc += bf2f(eb);
        }
        *(ushort4*)(Eb + (size_t)gm * NTGT + scol) = o;
        racc += __shfl_xor(racc, 1, 64);
        racc += __shfl_xor(racc, 2, 64);
        racc += __shfl_xor(racc, 4, 64);
        racc += __shfl_xor(racc, 8, 64);
        if (fr == 0) atomicAdd(&red[gm], racc);
      }
  } else {
    // split-K PV: fp32 partials, permuted float4 stores
    float* Pz = Cf + (size_t)blockIdx.z * NSRC * DIM;
#pragma unroll
    for (int i = 0; i < 8; ++i)
#pragma unroll
      for (int r = 0; r < 4; ++r) {
        const int gm = m0 + wm * 128 + i * 16 + kq * 4 + r;
        float4 v = make_float4(acc[i][0][r], acc[i][1][r], acc[i][2][r], acc[i][3][r]);
        *(float4*)(Pz + (size_t)gm * DIM + scol) = v;
      }
  }
#undef STAGE_A
#undef STAGE_B
#undef LDA1
#undef LDA8
#undef LDB2
#undef MFMA16
#undef PHASE
#undef SB0
#undef BARS
#undef LGKM2
#undef LGKM0
#undef VM4
}

// ---------------- launch ----------------
extern "C" void kernel_launch(void* const* d_in, const int* in_sizes, int n_in,
                              void* d_out, int out_size, void* d_ws, size_t ws_size,
                              hipStream_t stream) {
  const float* source = (const float*)d_in[0];
  const float* target = (const float*)d_in[1];
  const float* W_src  = (const float*)d_in[2];
  const float* b_src  = (const float*)d_in[3];
  const float* W_tgt  = (const float*)d_in[4];
  const float* b_tgt  = (const float*)d_in[5];
  const float* temp   = (const float*)d_in[6];

  float* out     = (float*)d_out;
  float* aligned = out;                         // [NSRC][DIM]
  float* Kout    = out + (size_t)NSRC * DIM;    // final K; staging for split-K partials
  float* parts   = Kout;                        // 4 x [NSRC][DIM] fp32 = exactly 64 MB

  char* ws = (char*)d_ws;
  unsigned short* src_b  = (unsigned short*)(ws + 0);
  unsigned short* tgt_b  = (unsigned short*)(ws + 8388608);
  unsigned short* Wsrc_b = (unsigned short*)(ws + 16777216);
  unsigned short* Wtgt_b = (unsigned short*)(ws + 18874368);
  unsigned short* sp_b   = (unsigned short*)(ws + 20971520);
  unsigned short* tp_b   = (unsigned short*)(ws + 29360128);
  unsigned short* tgtT_b = (unsigned short*)(ws + 37748736);
  unsigned short* E_b    = (unsigned short*)(ws + 46137344); // 32 MB
  float* sq_s  = (float*)(ws + 79691776);                    // 16 KB
  float* sq_t  = (float*)(ws + 79708160);                    // 16 KB
  float* rsums = (float*)(ws + 79724544);                    // 16 KB

  // 0) zero sq_s, sq_t, rsums (contiguous 48 KB)
  hipMemsetAsync(sq_s, 0, 3 * NSRC * sizeof(float), stream);

  // 1) conversions + permuted target transpose
  k_convert_all<<<10240, 256, 0, stream>>>(source, target, W_src, W_tgt,
                                           src_b, tgt_b, Wsrc_b, Wtgt_b);
  k_transpose_bf16<<<dim3(DIM / 32, NTGT / 32), dim3(32, 8), 0, stream>>>(target, tgtT_b, NTGT, DIM);

  // 2) both projections (z selects problem); outputs permuted in DIM; row-sumsq fused
  k_tile256<0, DIM><<<dim3(DIM / 256, NSRC / 256, 2), 512, 0, stream>>>(
      src_b, Wsrc_b, tgt_b, Wtgt_b, b_src, b_tgt, sp_b, tp_b,
      nullptr, nullptr, nullptr, nullptr, nullptr, sq_s, sq_t);

  // 3) score: E bf16 (permuted in NTGT) -> ws, row sums -> rsums
  k_tile256<1, DIM><<<dim3(NTGT / 256, NSRC / 256, 1), 512, 0, stream>>>(
      sp_b, tp_b, nullptr, nullptr, nullptr, nullptr, nullptr, nullptr,
      E_b, nullptr, sq_s, sq_t, temp, rsums, nullptr);

  // 4) E @ target: split-K x4 (chunk=1024), permuted float4 partials into d_out K region
  k_tile256<3, NTGT><<<dim3(DIM / 256, NSRC / 256, 4), 512, 0, stream>>>(
      E_b, tgtT_b, nullptr, nullptr, nullptr, nullptr, nullptr, nullptr,
      nullptr, parts, nullptr, nullptr, nullptr, nullptr, nullptr);

  // 5) finalize: aligned first (reads parts), then K (overwrites parts region)
  k_finalize_aligned<<<4096, 256, 0, stream>>>(parts, aligned, rsums);
  k_finalize_K<<<8192, 256, 0, stream>>>(E_b, Kout, rsums);
}